// Round 7
// baseline (211.928 us; speedup 1.0000x reference)
//
#include <hip/hip_runtime.h>

// NetVLAD fused kernel for MI355X (gfx950).
// Shapes: x[N=64][C=128][S=4096] fp32, conv_w[K=64][C=128], centroids[K=64][C=128].
// out[N][K*C] fp32.
//
// R13: de-confounded 4-block test = R10 grid/buffering + R12 VALU diet.
// Counter-calibration (R6): MfmaUtil 3.9% with known MFMA work implies
// ~0.92 GHz effective compute clock; VALUBusy 23% matches ~900 VALU-cyc
// /chunk/wave of software f2bf (R12 halved this); LDS pipe ~2000 cyc per
// block-chunk (gather 32xu16=768 biggest). R10's 4-block run saturated
// LDS+VALU (2x2000 cyc per 4.4us slot ~ 98% of pipe) -- with VALU halved,
// retest 4 blocks/CU:
//  - single-buffered x_cs (27.6 KB LDS), Pp=16, CH=4, 3 barriers/chunk
//  - 1024 blocks = exactly 4/CU by LDS and by VGPR (116 -> 4 waves/SIMD)
//  - __launch_bounds__(256,2): the proven no-spill register budget
//  - cvt_pk (v_cvt_pk_bf16_f32) for ALL f32->bf16 paths (R12)
// Certificates: VGPR==116, WRITE_SIZE~33MB, FETCH~66MB.
// Falsifier: main >= 72us => LDS-pipe saturation at 4 blocks; R12 stands.

#define Nn 64
#define Cc 128
#define Ss 4096
#define Kk 64
#define TS 64
#define CH 4
#define SB (TS*CH)
#define Pp 16   // s-slabs == partial buffers

typedef __attribute__((ext_vector_type(8))) short bf16x8;
typedef __attribute__((ext_vector_type(4))) float f32x4;

// HW packed f32->bf16 (RNE): dst.lo = bf16(a), dst.hi = bf16(b). 1 VALU op.
__device__ __forceinline__ unsigned cvt2(float a, float b) {
  unsigned r;
  asm("v_cvt_pk_bf16_f32 %0, %1, %2" : "=v"(r) : "v"(a), "v"(b));
  return r;
}

// Barrier that waits only LDS ops (lgkmcnt), NOT in-flight global loads (vmcnt).
// Correct: cross-wave communication is exclusively through LDS; global loads
// land in private registers.
__device__ __forceinline__ void bar_lds() {
  asm volatile("s_waitcnt lgkmcnt(0)\n\ts_barrier" ::: "memory");
}

// LDS strides in halves. Rows 144B (multiple of 16B) for aligned b128 access.
#define XCS_STR 72    // x_cs[128][72]
#define AKS_STR 72    // a_ks[64][72]

__launch_bounds__(256, 2)
__global__ void netvlad_main(const float* __restrict__ x,
                             const float* __restrict__ w,
                             float* __restrict__ vlad,   // [P][N][K][C] partials, or [N][K][C] zeroed (atomic)
                             float* __restrict__ asum,   // [P][N][K] partials,    or [N][K] zeroed (atomic)
                             int use_atomic)
{
  __shared__ __align__(16) unsigned short x_cs[Cc][XCS_STR];  // x[c][s], SINGLE buffer
  __shared__ __align__(16) unsigned short a_ks[Kk][AKS_STR];  // a[k][s]

  const int t   = threadIdx.x;
  const int wv  = t >> 6;          // wave 0..3
  const int l15 = t & 15;
  const int l4  = (t >> 4) & 3;    // lane quad within wave
  const int n   = blockIdx.y;
  const int sb  = blockIdx.x;      // s-slab 0..15
  const size_t xbase = (size_t)n * Cc * Ss;

  // ---- preload W fragments into registers (A-operand of P1) ----
  // A[m=k][kd=c]: lane holds A[16*mt + l15][32*q + 8*l4 + j], j=0..7
  bf16x8 wfrag[4][4];
#pragma unroll
  for (int mt = 0; mt < 4; ++mt) {
#pragma unroll
    for (int q = 0; q < 4; ++q) {
      const float* wp = w + (16*mt + l15) * Cc + 32*q + 8*l4;
      float4 a = *(const float4*)wp;
      float4 b = *(const float4*)(wp + 4);
      int4 pk = make_int4((int)cvt2(a.x, a.y), (int)cvt2(a.z, a.w),
                          (int)cvt2(b.x, b.y), (int)cvt2(b.z, b.w));
      wfrag[mt][q] = *(bf16x8*)&pk;
    }
  }

  // persistent accumulators
  f32x4 acc3[4][2];                 // [mt(k-tile)][tc(c-tile within wave's 32c)]
#pragma unroll
  for (int mt = 0; mt < 4; ++mt)
#pragma unroll
    for (int tc = 0; tc < 2; ++tc) acc3[mt][tc] = (f32x4){0.f,0.f,0.f,0.f};
  float asum_reg[4][4];             // [mt][r]
#pragma unroll
  for (int mt = 0; mt < 4; ++mt)
#pragma unroll
    for (int r = 0; r < 4; ++r) asum_reg[mt][r] = 0.f;

  // ---- prologue: prefetch chunk 0 into registers (constant-indexed v[8]) ----
  const int s4 = 4 * l15;
  const int cb = t >> 4;           // 0..15
  const float* px0 = x + xbase + (size_t)cb * Ss + sb * SB + s4;
  float4 v[8];
#pragma unroll
  for (int it = 0; it < 8; ++it)
    v[it] = *(const float4*)(px0 + (size_t)(16 * it) * Ss);

  for (int ch = 0; ch < CH; ++ch) {
    // ---- convert prefetched regs -> x_cs bf16 ([c][s]) ----
    // safe: previous chunk's BC barrier drained all x_cs/a_ks readers
#pragma unroll
    for (int it = 0; it < 8; ++it) {
      float4 vv = v[it];
      unsigned p0 = cvt2(vv.x, vv.y);
      unsigned p1 = cvt2(vv.z, vv.w);
      *(int2*)&x_cs[cb + 16*it][s4] = make_int2((int)p0, (int)p1);
    }
    // ---- issue next chunk's loads; they stay in flight across barriers ----
    if (ch + 1 < CH) {
      const float* px = px0 + (ch + 1) * TS;
#pragma unroll
      for (int it = 0; it < 8; ++it)
        v[it] = *(const float4*)(px + (size_t)(16 * it) * Ss);
    }
    bar_lds();   // BA: x_cs visible to all waves

    // ---- build P1 B-frags directly in registers from x_cs columns ----
    // bfr[q][j'] = x[c = 32q + 8*l4 + j'][s = 16*wv + l15]
    // rotation (i+2*l4)&7 -> each instruction's 64 lanes tile all 32 banks
    bf16x8 bfr[4];
#pragma unroll
    for (int j = 0; j < 4; ++j) {
      const int c8 = 32*j + 8*l4;
      unsigned short h[8];
#pragma unroll
      for (int i = 0; i < 8; ++i) {
        const int i2 = (i + 2*l4) & 7;
        h[i2] = x_cs[c8 + i2][16*wv + l15];
      }
      bf16x8 f;
#pragma unroll
      for (int i = 0; i < 8; ++i) f[i] = (short)h[i];
      bfr[j] = f;
    }

    // ---- P1: logits tile. wave wv owns s-tile [16*wv,16*wv+16), all 64 k ----
    f32x4 acc1[4];
#pragma unroll
    for (int mt = 0; mt < 4; ++mt) acc1[mt] = (f32x4){0.f,0.f,0.f,0.f};
#pragma unroll
    for (int q = 0; q < 4; ++q) {
#pragma unroll
      for (int mt = 0; mt < 4; ++mt)
        acc1[mt] = __builtin_amdgcn_mfma_f32_16x16x32_bf16(wfrag[mt][q], bfr[q], acc1[mt], 0, 0, 0);
    }

    // ---- softmax over k, fully in-wave ----
    // C/D layout: col s = 16*wv + l15, row k = 16*mt + 4*l4 + r
    float e[4][4];
    float cs = 0.f;
#pragma unroll
    for (int mt = 0; mt < 4; ++mt)
#pragma unroll
      for (int r = 0; r < 4; ++r) {
        float ev = __expf(acc1[mt][r]);
        e[mt][r] = ev;
        cs += ev;
      }
    cs += __shfl_xor(cs, 16, 64);
    cs += __shfl_xor(cs, 32, 64);
    const float inv = 1.0f / cs;
#pragma unroll
    for (int mt = 0; mt < 4; ++mt)
#pragma unroll
      for (int r = 0; r < 4; ++r) {
        float an = e[mt][r] * inv;
        asum_reg[mt][r] += an;
        a_ks[16*mt + 4*l4 + r][16*wv + l15] = (unsigned short)cvt2(an, an);
      }
    bar_lds();   // BB: a_ks ready

    // ---- P3: vlad += A @ X^T. wave wv owns c in [32*wv, 32*wv+32) ----
#pragma unroll
    for (int q2 = 0; q2 < 2; ++q2) {
      bf16x8 afr[4];
#pragma unroll
      for (int mt = 0; mt < 4; ++mt)
        afr[mt] = *(bf16x8*)&a_ks[16*mt + l15][32*q2 + 8*l4];
#pragma unroll
      for (int tc = 0; tc < 2; ++tc) {
        bf16x8 bfx = *(bf16x8*)&x_cs[32*wv + 16*tc + l15][32*q2 + 8*l4];
#pragma unroll
        for (int mt = 0; mt < 4; ++mt)
          acc3[mt][tc] = __builtin_amdgcn_mfma_f32_16x16x32_bf16(afr[mt], bfx, acc3[mt][tc], 0, 0, 0);
      }
    }
    bar_lds();   // BC: P3's x_cs/a_ks reads drained before next convert/softmax
  }

  // ---- block epilogue: asum cross-wave reduction via LDS, then stores ----
  // (loop's final BC already drained all a_ks readers)
  float* asml = (float*)a_ks;
#pragma unroll
  for (int mt = 0; mt < 4; ++mt) {
#pragma unroll
    for (int r = 0; r < 4; ++r) {
      float vv = asum_reg[mt][r];
      vv += __shfl_xor(vv, 1, 64);
      vv += __shfl_xor(vv, 2, 64);
      vv += __shfl_xor(vv, 4, 64);
      vv += __shfl_xor(vv, 8, 64);
      if (l15 == 0) asml[wv * Kk + 16*mt + 4*l4 + r] = vv;
    }
  }
  bar_lds();
  if (t < Kk) {
    float s = asml[t] + asml[Kk + t] + asml[2*Kk + t] + asml[3*Kk + t];
    if (use_atomic) atomicAdd(&asum[n * Kk + t], s);
    else            asum[((size_t)sb * Nn + n) * Kk + t] = s;
  }

  if (use_atomic) {
#pragma unroll
    for (int mt = 0; mt < 4; ++mt)
#pragma unroll
      for (int tc = 0; tc < 2; ++tc)
#pragma unroll
        for (int r = 0; r < 4; ++r) {
          const int k = 16*mt + 4*l4 + r;
          const int c = 32*wv + 16*tc + l15;
          atomicAdd(&vlad[((size_t)n * Kk + k) * Cc + c], acc3[mt][tc][r]);
        }
  } else {
    float* vp = vlad + ((size_t)sb * Nn + n) * (Kk * Cc);
#pragma unroll
    for (int mt = 0; mt < 4; ++mt)
#pragma unroll
      for (int tc = 0; tc < 2; ++tc)
#pragma unroll
        for (int r = 0; r < 4; ++r) {
          const int k = 16*mt + 4*l4 + r;
          const int c = 32*wv + 16*tc + l15;
          vp[k * Cc + c] = acc3[mt][tc][r];   // streaming, coalesced per 16 lanes
        }
  }
}

__global__ void netvlad_epilogue(const float* __restrict__ vlad,  // [P][N][K][C] or [N][K][C]
                                 const float* __restrict__ asum,  // [P][N][K]    or [N][K]
                                 const float* __restrict__ cent,
                                 float* __restrict__ out,
                                 int nparts)
{
  const int n  = blockIdx.x;
  const int k  = 16*blockIdx.y + (threadIdx.x >> 4);
  const int cq = threadIdx.x & 15;   // 16 threads per k, 8 c each

  float ak = 0.f;
  float4 x0 = make_float4(0.f, 0.f, 0.f, 0.f);
  float4 x1 = make_float4(0.f, 0.f, 0.f, 0.f);
  for (int p = 0; p < nparts; ++p) {
    ak += asum[((size_t)p * Nn + n) * Kk + k];
    const float* vp = vlad + (((size_t)p * Nn + n) * Kk + k) * Cc + 8*cq;
    float4 a0 = *(const float4*)vp;
    float4 a1 = *(const float4*)(vp + 4);
    x0.x += a0.x; x0.y += a0.y; x0.z += a0.z; x0.w += a0.w;
    x1.x += a1.x; x1.y += a1.y; x1.z += a1.z; x1.w += a1.w;
  }

  const size_t cbse = (size_t)k * Cc + 8*cq;
  float4 c0 = *(const float4*)(cent + cbse);
  float4 c1 = *(const float4*)(cent + cbse + 4);
  float4 r0, r1;
  r0.x = x0.x - ak*c0.x; r0.y = x0.y - ak*c0.y; r0.z = x0.z - ak*c0.z; r0.w = x0.w - ak*c0.w;
  r1.x = x1.x - ak*c1.x; r1.y = x1.y - ak*c1.y; r1.z = x1.z - ak*c1.z; r1.w = x1.w - ak*c1.w;
  float ss = r0.x*r0.x + r0.y*r0.y + r0.z*r0.z + r0.w*r0.w
           + r1.x*r1.x + r1.y*r1.y + r1.z*r1.z + r1.w*r1.w;
  ss += __shfl_xor(ss, 1, 64);
  ss += __shfl_xor(ss, 2, 64);
  ss += __shfl_xor(ss, 4, 64);
  ss += __shfl_xor(ss, 8, 64);
  // intra-norm; global norm is exactly sqrt(K)=8 since rows are unit norm
  const float rn = rsqrtf(ss) * 0.125f;
  r0.x *= rn; r0.y *= rn; r0.z *= rn; r0.w *= rn;
  r1.x *= rn; r1.y *= rn; r1.z *= rn; r1.w *= rn;
  float* op = out + (size_t)n * (Kk * Cc) + (size_t)k * Cc + 8*cq;
  *(float4*)op = r0;
  *(float4*)(op + 4) = r1;
}

extern "C" void kernel_launch(void* const* d_in, const int* in_sizes, int n_in,
                              void* d_out, int out_size, void* d_ws, size_t ws_size,
                              hipStream_t stream)
{
  const float* x    = (const float*)d_in[0];
  const float* w    = (const float*)d_in[1];
  const float* cent = (const float*)d_in[2];
  float* out = (float*)d_out;

  const size_t vlad_elems_p = (size_t)Pp * Nn * Kk * Cc;
  const size_t asum_elems_p = (size_t)Pp * Nn * Kk;
  const size_t need = (vlad_elems_p + asum_elems_p) * sizeof(float);

  if (ws_size >= need) {
    // partial-sum path: no atomics, no memset
    float* vlad_part = (float*)d_ws;
    float* asum_part = vlad_part + vlad_elems_p;
    netvlad_main<<<dim3(Pp, Nn), 256, 0, stream>>>(x, w, vlad_part, asum_part, 0);
    netvlad_epilogue<<<dim3(Nn, 4), 256, 0, stream>>>(vlad_part, asum_part, cent, out, Pp);
  } else {
    // atomic fallback
    float* vlad = (float*)d_ws;
    float* asum = vlad + (size_t)Nn * Kk * Cc;
    const size_t zbytes = ((size_t)Nn * Kk * Cc + (size_t)Nn * Kk) * sizeof(float);
    hipMemsetAsync(d_ws, 0, zbytes, stream);
    netvlad_main<<<dim3(Pp, Nn), 256, 0, stream>>>(x, w, vlad, asum, 1);
    netvlad_epilogue<<<dim3(Nn, 4), 256, 0, stream>>>(vlad, asum, cent, out, 1);
  }
}

// Round 8
// 206.662 us; speedup vs baseline: 1.0255x; 1.0255x over previous
//
#include <hip/hip_runtime.h>

// NetVLAD fused kernel for MI355X (gfx950).
// Shapes: x[N=64][C=128][S=4096] fp32, conv_w[K=64][C=128], centroids[K=64][C=128].
// out[N][K*C] fp32.
//
// R14 = R12 (best: dur 207.4, main ~70us) + dword-pair gather.
// Evidence: dur == main + 137±4 across 7 rounds; only chain-shortening has
// ever helped (cvt_pk: -3us in two structures). Biggest remaining chain
// segment = P1 gather: 32 ds_read_u16/lane/chunk + packing. Rewrite:
//  - read column dwords (lane pairs s,s^1 share -> LDS broadcast)
//  - two consecutive c-rows per base (+0 / +144B imm) -> LLVM DS combiner
//    fuses to ds_read2_b32 (offsets 0/36 dwords): 32 -> 16 (8 fused) reads
//  - pack with v_perm_b32 (selector by s-parity): f[2k],f[2k+1] = rows
//    c8+2k, c8+2k+1 -> same fragment order as before
//  - bank rotation kept at pair granularity ((p+l4)&3: quads at {0,8,16,24})
// Everything else IDENTICAL to R12: Pp=8, CH=8, TS=64, dbuf x_cs, 2 lgkm-only
// barriers/chunk, cvt_pk f32->bf16, scratch-safe v[8], partial-sum stores.
// Certificates: VGPR<=120, WRITE 16.4MB, FETCH ~66MB.

#define Nn 64
#define Cc 128
#define Ss 4096
#define Kk 64
#define TS 64
#define CH 8
#define SB (TS*CH)
#define Pp 8    // s-slabs == partial buffers

typedef __attribute__((ext_vector_type(8))) short bf16x8;
typedef __attribute__((ext_vector_type(4))) float f32x4;

// HW packed f32->bf16 (RNE): dst.lo = bf16(a), dst.hi = bf16(b). 1 VALU op.
__device__ __forceinline__ unsigned cvt2(float a, float b) {
  unsigned r;
  asm("v_cvt_pk_bf16_f32 %0, %1, %2" : "=v"(r) : "v"(a), "v"(b));
  return r;
}

// Barrier that waits only LDS ops (lgkmcnt), NOT in-flight global loads (vmcnt).
// Correct: cross-wave communication is exclusively through LDS; global loads
// land in private registers.
__device__ __forceinline__ void bar_lds() {
  asm volatile("s_waitcnt lgkmcnt(0)\n\ts_barrier" ::: "memory");
}

// LDS strides in halves. Rows 144B (multiple of 16B) for aligned b128 access.
#define XCS_STR 72    // x_cs[2][128][72]
#define AKS_STR 72    // a_ks[64][72]

__launch_bounds__(256, 2)
__global__ void netvlad_main(const float* __restrict__ x,
                             const float* __restrict__ w,
                             float* __restrict__ vlad,   // [P][N][K][C] partials, or [N][K][C] zeroed (atomic)
                             float* __restrict__ asum,   // [P][N][K] partials,    or [N][K] zeroed (atomic)
                             int use_atomic)
{
  __shared__ __align__(16) unsigned short x_cs[2][Cc][XCS_STR];  // x[c][s], double-buffered
  __shared__ __align__(16) unsigned short a_ks[Kk][AKS_STR];     // a[k][s]

  const int t   = threadIdx.x;
  const int wv  = t >> 6;          // wave 0..3
  const int l15 = t & 15;
  const int l4  = (t >> 4) & 3;    // lane quad within wave
  const int n   = blockIdx.y;
  const int sb  = blockIdx.x;      // s-slab 0..7
  const size_t xbase = (size_t)n * Cc * Ss;

  // P1 gather helpers: column dword index and byte-select for v_perm.
  // column halves index = 16*wv + l15; dword = 8*wv + (l15>>1).
  const int cdw = 8*wv + (l15 >> 1);
  // perm(a=row2k+1, b=row2k, sel): even s-col -> bytes [b0,b1,a0,a1],
  // odd s-col -> [b2,b3,a2,a3].
  const unsigned sel = (l15 & 1) ? 0x07060302u : 0x05040100u;

  // ---- preload W fragments into registers (A-operand of P1) ----
  // A[m=k][kd=c]: lane holds A[16*mt + l15][32*q + 8*l4 + j], j=0..7
  bf16x8 wfrag[4][4];
#pragma unroll
  for (int mt = 0; mt < 4; ++mt) {
#pragma unroll
    for (int q = 0; q < 4; ++q) {
      const float* wp = w + (16*mt + l15) * Cc + 32*q + 8*l4;
      float4 a = *(const float4*)wp;
      float4 b = *(const float4*)(wp + 4);
      int4 pk = make_int4((int)cvt2(a.x, a.y), (int)cvt2(a.z, a.w),
                          (int)cvt2(b.x, b.y), (int)cvt2(b.z, b.w));
      wfrag[mt][q] = *(bf16x8*)&pk;
    }
  }

  // persistent accumulators
  f32x4 acc3[4][2];                 // [mt(k-tile)][tc(c-tile within wave's 32c)]
#pragma unroll
  for (int mt = 0; mt < 4; ++mt)
#pragma unroll
    for (int tc = 0; tc < 2; ++tc) acc3[mt][tc] = (f32x4){0.f,0.f,0.f,0.f};
  float asum_reg[4][4];             // [mt][r]
#pragma unroll
  for (int mt = 0; mt < 4; ++mt)
#pragma unroll
    for (int r = 0; r < 4; ++r) asum_reg[mt][r] = 0.f;

  // ---- prologue: prefetch chunk 0 into registers (constant-indexed v[8]) ----
  const int s4 = 4 * l15;
  const int cb = t >> 4;           // 0..15
  const float* px0 = x + xbase + (size_t)cb * Ss + sb * SB + s4;
  float4 v[8];
#pragma unroll
  for (int it = 0; it < 8; ++it)
    v[it] = *(const float4*)(px0 + (size_t)(16 * it) * Ss);

  for (int ch = 0; ch < CH; ++ch) {
    const int buf = ch & 1;

    // ---- convert prefetched regs -> x_cs[buf] bf16 ([c][s]) ----
#pragma unroll
    for (int it = 0; it < 8; ++it) {
      float4 vv = v[it];
      unsigned p0 = cvt2(vv.x, vv.y);
      unsigned p1 = cvt2(vv.z, vv.w);
      *(int2*)&x_cs[buf][cb + 16*it][s4] = make_int2((int)p0, (int)p1);
    }
    // ---- issue next chunk's loads; they stay in flight across bar_lds ----
    if (ch + 1 < CH) {
      const float* px = px0 + (ch + 1) * TS;
#pragma unroll
      for (int it = 0; it < 8; ++it)
        v[it] = *(const float4*)(px + (size_t)(16 * it) * Ss);
    }
    bar_lds();   // BA: x_cs[buf] visible; prior a_ks readers drained

    // ---- build P1 B-frags from x_cs[buf] columns: dword-pair reads ----
    // bfr[q][j'] = x[c = 32q + 8*l4 + j'][s = 16*wv + l15]
    // Lane pairs (s even/odd) read the SAME dword (LDS broadcast); rows
    // 2k,2k+1 read off one base (+0/+144B) -> ds_read2_b32 fusable.
    // Pair rotation (p+l4)&3 spreads quads across banks {0,8,16,24}.
    bf16x8 bfr[4];
#pragma unroll
    for (int j = 0; j < 4; ++j) {
      const int c8 = 32*j + 8*l4;
      unsigned dlo[4], dhi[4];
#pragma unroll
      for (int p = 0; p < 4; ++p) {
        const int pr = (p + l4) & 3;
        const unsigned short* rp = &x_cs[buf][c8 + 2*pr][2*cdw];
        dlo[pr] = *(const unsigned*)rp;                 // row c8+2pr
        dhi[pr] = *(const unsigned*)(rp + XCS_STR);     // row c8+2pr+1
      }
      int4 pk;
      pk.x = (int)__builtin_amdgcn_perm(dhi[0], dlo[0], sel);  // f0,f1
      pk.y = (int)__builtin_amdgcn_perm(dhi[1], dlo[1], sel);  // f2,f3
      pk.z = (int)__builtin_amdgcn_perm(dhi[2], dlo[2], sel);  // f4,f5
      pk.w = (int)__builtin_amdgcn_perm(dhi[3], dlo[3], sel);  // f6,f7
      bfr[j] = *(bf16x8*)&pk;
    }

    // ---- P1: logits tile. wave wv owns s-tile [16*wv,16*wv+16), all 64 k ----
    f32x4 acc1[4];
#pragma unroll
    for (int mt = 0; mt < 4; ++mt) acc1[mt] = (f32x4){0.f,0.f,0.f,0.f};
#pragma unroll
    for (int q = 0; q < 4; ++q) {
#pragma unroll
      for (int mt = 0; mt < 4; ++mt)
        acc1[mt] = __builtin_amdgcn_mfma_f32_16x16x32_bf16(wfrag[mt][q], bfr[q], acc1[mt], 0, 0, 0);
    }

    // ---- softmax over k, fully in-wave ----
    // C/D layout: col s = 16*wv + l15, row k = 16*mt + 4*l4 + r
    float e[4][4];
    float cs = 0.f;
#pragma unroll
    for (int mt = 0; mt < 4; ++mt)
#pragma unroll
      for (int r = 0; r < 4; ++r) {
        float ev = __expf(acc1[mt][r]);
        e[mt][r] = ev;
        cs += ev;
      }
    cs += __shfl_xor(cs, 16, 64);
    cs += __shfl_xor(cs, 32, 64);
    const float inv = 1.0f / cs;
#pragma unroll
    for (int mt = 0; mt < 4; ++mt)
#pragma unroll
      for (int r = 0; r < 4; ++r) {
        float an = e[mt][r] * inv;
        asum_reg[mt][r] += an;
        a_ks[16*mt + 4*l4 + r][16*wv + l15] = (unsigned short)cvt2(an, an);
      }
    bar_lds();   // BB: a_ks ready

    // ---- P3: vlad += A @ X^T. wave wv owns c in [32*wv, 32*wv+32) ----
#pragma unroll
    for (int q2 = 0; q2 < 2; ++q2) {
      bf16x8 afr[4];
#pragma unroll
      for (int mt = 0; mt < 4; ++mt)
        afr[mt] = *(bf16x8*)&a_ks[16*mt + l15][32*q2 + 8*l4];
#pragma unroll
      for (int tc = 0; tc < 2; ++tc) {
        bf16x8 bfx = *(bf16x8*)&x_cs[buf][32*wv + 16*tc + l15][32*q2 + 8*l4];
#pragma unroll
        for (int mt = 0; mt < 4; ++mt)
          acc3[mt][tc] = __builtin_amdgcn_mfma_f32_16x16x32_bf16(afr[mt], bfx, acc3[mt][tc], 0, 0, 0);
      }
    }
    // no end-of-chunk barrier: next convert writes x_cs[1-buf]; rewrites of
    // x_cs[buf] (ch+2) and a_ks (ch+1) are fenced by BA/BB of chunk ch+1.
  }

  // ---- block epilogue: asum cross-wave reduction via LDS, then stores ----
  bar_lds();                    // all P3 a_ks reads drained before reuse
  float* asml = (float*)a_ks;
#pragma unroll
  for (int mt = 0; mt < 4; ++mt) {
#pragma unroll
    for (int r = 0; r < 4; ++r) {
      float vv = asum_reg[mt][r];
      vv += __shfl_xor(vv, 1, 64);
      vv += __shfl_xor(vv, 2, 64);
      vv += __shfl_xor(vv, 4, 64);
      vv += __shfl_xor(vv, 8, 64);
      if (l15 == 0) asml[wv * Kk + 16*mt + 4*l4 + r] = vv;
    }
  }
  bar_lds();
  if (t < Kk) {
    float s = asml[t] + asml[Kk + t] + asml[2*Kk + t] + asml[3*Kk + t];
    if (use_atomic) atomicAdd(&asum[n * Kk + t], s);
    else            asum[((size_t)sb * Nn + n) * Kk + t] = s;
  }

  if (use_atomic) {
#pragma unroll
    for (int mt = 0; mt < 4; ++mt)
#pragma unroll
      for (int tc = 0; tc < 2; ++tc)
#pragma unroll
        for (int r = 0; r < 4; ++r) {
          const int k = 16*mt + 4*l4 + r;
          const int c = 32*wv + 16*tc + l15;
          atomicAdd(&vlad[((size_t)n * Kk + k) * Cc + c], acc3[mt][tc][r]);
        }
  } else {
    float* vp = vlad + ((size_t)sb * Nn + n) * (Kk * Cc);
#pragma unroll
    for (int mt = 0; mt < 4; ++mt)
#pragma unroll
      for (int tc = 0; tc < 2; ++tc)
#pragma unroll
        for (int r = 0; r < 4; ++r) {
          const int k = 16*mt + 4*l4 + r;
          const int c = 32*wv + 16*tc + l15;
          vp[k * Cc + c] = acc3[mt][tc][r];   // streaming, coalesced per 16 lanes
        }
  }
}

__global__ void netvlad_epilogue(const float* __restrict__ vlad,  // [P][N][K][C] or [N][K][C]
                                 const float* __restrict__ asum,  // [P][N][K]    or [N][K]
                                 const float* __restrict__ cent,
                                 float* __restrict__ out,
                                 int nparts)
{
  const int n  = blockIdx.x;
  const int k  = 16*blockIdx.y + (threadIdx.x >> 4);
  const int cq = threadIdx.x & 15;   // 16 threads per k, 8 c each

  float ak = 0.f;
  float4 x0 = make_float4(0.f, 0.f, 0.f, 0.f);
  float4 x1 = make_float4(0.f, 0.f, 0.f, 0.f);
  for (int p = 0; p < nparts; ++p) {
    ak += asum[((size_t)p * Nn + n) * Kk + k];
    const float* vp = vlad + (((size_t)p * Nn + n) * Kk + k) * Cc + 8*cq;
    float4 a0 = *(const float4*)vp;
    float4 a1 = *(const float4*)(vp + 4);
    x0.x += a0.x; x0.y += a0.y; x0.z += a0.z; x0.w += a0.w;
    x1.x += a1.x; x1.y += a1.y; x1.z += a1.z; x1.w += a1.w;
  }

  const size_t cbse = (size_t)k * Cc + 8*cq;
  float4 c0 = *(const float4*)(cent + cbse);
  float4 c1 = *(const float4*)(cent + cbse + 4);
  float4 r0, r1;
  r0.x = x0.x - ak*c0.x; r0.y = x0.y - ak*c0.y; r0.z = x0.z - ak*c0.z; r0.w = x0.w - ak*c0.w;
  r1.x = x1.x - ak*c1.x; r1.y = x1.y - ak*c1.y; r1.z = x1.z - ak*c1.z; r1.w = x1.w - ak*c1.w;
  float ss = r0.x*r0.x + r0.y*r0.y + r0.z*r0.z + r0.w*r0.w
           + r1.x*r1.x + r1.y*r1.y + r1.z*r1.z + r1.w*r1.w;
  ss += __shfl_xor(ss, 1, 64);
  ss += __shfl_xor(ss, 2, 64);
  ss += __shfl_xor(ss, 4, 64);
  ss += __shfl_xor(ss, 8, 64);
  // intra-norm; global norm is exactly sqrt(K)=8 since rows are unit norm
  const float rn = rsqrtf(ss) * 0.125f;
  r0.x *= rn; r0.y *= rn; r0.z *= rn; r0.w *= rn;
  r1.x *= rn; r1.y *= rn; r1.z *= rn; r1.w *= rn;
  float* op = out + (size_t)n * (Kk * Cc) + (size_t)k * Cc + 8*cq;
  *(float4*)op = r0;
  *(float4*)(op + 4) = r1;
}

extern "C" void kernel_launch(void* const* d_in, const int* in_sizes, int n_in,
                              void* d_out, int out_size, void* d_ws, size_t ws_size,
                              hipStream_t stream)
{
  const float* x    = (const float*)d_in[0];
  const float* w    = (const float*)d_in[1];
  const float* cent = (const float*)d_in[2];
  float* out = (float*)d_out;

  const size_t vlad_elems_p = (size_t)Pp * Nn * Kk * Cc;
  const size_t asum_elems_p = (size_t)Pp * Nn * Kk;
  const size_t need = (vlad_elems_p + asum_elems_p) * sizeof(float);

  if (ws_size >= need) {
    // partial-sum path: no atomics, no memset
    float* vlad_part = (float*)d_ws;
    float* asum_part = vlad_part + vlad_elems_p;
    netvlad_main<<<dim3(Pp, Nn), 256, 0, stream>>>(x, w, vlad_part, asum_part, 0);
    netvlad_epilogue<<<dim3(Nn, 4), 256, 0, stream>>>(vlad_part, asum_part, cent, out, Pp);
  } else {
    // atomic fallback
    float* vlad = (float*)d_ws;
    float* asum = vlad + (size_t)Nn * Kk * Cc;
    const size_t zbytes = ((size_t)Nn * Kk * Cc + (size_t)Nn * Kk) * sizeof(float);
    hipMemsetAsync(d_ws, 0, zbytes, stream);
    netvlad_main<<<dim3(Pp, Nn), 256, 0, stream>>>(x, w, vlad, asum, 1);
    netvlad_epilogue<<<dim3(Nn, 4), 256, 0, stream>>>(vlad, asum, cent, out, 1);
  }
}